// Round 14
// baseline (29.941 us; speedup 1.0000x reference)
//
#include <hip/hip_runtime.h>
#include <hip/hip_bf16.h>

#define IN_F   4096
#define OUT_F  11008
#define BATCH  32
#define NTILE  64
#define KSPLIT 4
#define GRID_N (OUT_F / NTILE)    // 172

typedef __attribute__((ext_vector_type(8))) short  bf16x8;
typedef __attribute__((ext_vector_type(4))) float  f32x4;
typedef __attribute__((ext_vector_type(4))) int    i32x4;
typedef __attribute__((ext_vector_type(4))) float  float4v;

static __device__ __constant__ float NF4_LEVELS[16] = {
    -1.0f, -0.6961928009986877f, -0.5250730514526367f, -0.39491748809814453f,
    -0.28444138169288635f, -0.18477343022823334f, -0.09105003625154495f, 0.0f,
    0.07958029955625534f, 0.16093020141124725f, 0.24611230194568634f,
    0.33791524171829224f, 0.44070982933044434f, 0.5626170039176941f,
    0.7229568362236023f, 1.0f};

// ---------------------------------------------------------------------------
// Prelude (408 blocks):
//   bid <  64: A-fragment streams in MFMA order:
//     frag[st][kb][lane] (16B) = x[st*16+(lane&15)][kb*32+(lane>>4)*8..+8) bf16
//   bid >= 64: out[b][o] = bias[o]  (base for gemm atomics)
// ---------------------------------------------------------------------------
__global__ void prelude_kernel(const float* __restrict__ x,
                               const float* __restrict__ bias,
                               unsigned short* __restrict__ frag,
                               float* __restrict__ out) {
    const int bid = blockIdx.x, tid = threadIdx.x;
    if (bid < 64) {
        int T  = bid * 256 + tid;
        int st = T >> 13;
        int kb = (T >> 6) & 127;
        int l  = T & 63;
        int row = st * 16 + (l & 15);
        int k0  = kb * 32 + (l >> 4) * 8;
        const float* src = x + (size_t)row * IN_F + k0;
        unsigned w[4];
        #pragma unroll
        for (int e = 0; e < 4; ++e) {
            unsigned lo = __builtin_bit_cast(unsigned short, __float2bfloat16(src[2 * e]));
            unsigned hi = __builtin_bit_cast(unsigned short, __float2bfloat16(src[2 * e + 1]));
            w[e] = lo | (hi << 16);
        }
        i32x4 v = { (int)w[0], (int)w[1], (int)w[2], (int)w[3] };
        *reinterpret_cast<i32x4*>(frag + ((size_t)st * 8192 + kb * 64 + l) * 8) = v;
    } else {
        int t2 = (bid - 64) * 256 + tid;     // [0, 88064)
        int i  = t2 * 4;
        int o  = i % OUT_F;
        float4v b = *reinterpret_cast<const float4v*>(bias + o);
        *reinterpret_cast<float4v*>(out + i) = b;
    }
}

// ---------------------------------------------------------------------------
// Main: grid (172,4) = 688 blocks, 4 waves, 36KB LDS, ~4 blocks/CU.
// BARRIER-FREE K-loop (R13 structure). Block = 64 out-rows x 1024 k.
// Wave w owns k-slice [by*1024 + w*256, +256) = 2 scale groups, covers all
// 64 rows (4 strips) x 32 batch: 64 MFMA/wave. Wave-private: tabu copy,
// code buffer (2048 dw), scales in registers. One barrier total (reduce).
//
// Staging: 32 loads/wave; load i covers rows bb*16+2*(i&7)... two 512B row
//   segments each (lane>>5 = row parity, j = lane&31 = code-dword index,
//   j covers slice-k [8j, 8j+8)).  Compact 4 int32 -> 1 code dword; store at
//   (row*32 + sigma(j)) ^ ((row&7)<<2), sigma(j)=(j&0x10)|((j&3)<<2)|((j>>2)&3)
//   [t/g field swap].  Reader: ds_read_b128 at (row*32+grp*16+g*4)^((row&7)<<2)
//   yields ksteps t=0..3 (XOR touches bits 2-4 only; +t in bits 0-1 safe).
//   Writer 2-way banks, reader 2-way (8 XOR slots x 4 banks, 16 lanes). Free.
// Epilogue: red aliases wave's own dead code region, slot = b*64 + o
//   (batch-major -> conflict-free reads, coalesced 256B atomics).
// ---------------------------------------------------------------------------
__global__ __launch_bounds__(256, 4) void nf4_gemm_kernel(
        const int* __restrict__ packed,
        const float* __restrict__ scales,
        const unsigned short* __restrict__ frag,
        float* __restrict__ out)
{
    __shared__ unsigned lds[9216];   // 1024 tabu (4x256) | 8192 codes (4x2048)

    const int tid  = threadIdx.x;
    const int wave = tid >> 6;
    const int lane = tid & 63;
    const int col  = lane & 15;
    const int g    = lane >> 4;

    const int n0 = blockIdx.x * NTILE;
    const int by = blockIdx.y;

    // ---- wave-private tabu ----
    #pragma unroll
    for (int q = 0; q < 4; ++q) {
        int e = q * 64 + lane;
        unsigned lo = __builtin_bit_cast(unsigned short, __float2bfloat16(NF4_LEVELS[e & 15]));
        unsigned hi = __builtin_bit_cast(unsigned short, __float2bfloat16(NF4_LEVELS[(e >> 4) & 15]));
        lds[wave * 256 + e] = lo | (hi << 16);
    }

    // ---- per-lane scales: rows st*16+col, groups by*8+wave*2+{0,1} ----
    float2 scp[4];
    #pragma unroll
    for (int st = 0; st < 4; ++st)
        scp[st] = *reinterpret_cast<const float2*>(
            scales + (size_t)(n0 + st * 16 + col) * 32 + by * 8 + wave * 2);

    // ---- staging (strip-batches of 16 rows = 8 loads) ----
    #define SLOAD(bb, sr)                                                      \
        _Pragma("unroll")                                                      \
        for (int ii = 0; ii < 8; ++ii) {                                       \
            int row = (bb) * 16 + 2 * ii + (lane >> 5);                        \
            sr[ii] = *reinterpret_cast<const i32x4*>(                          \
                packed + (size_t)(n0 + row) * (IN_F / 2)                       \
                       + by * 512 + wave * 128 + (lane & 31) * 4);             \
        }

    #define SWRITE(bb, sr)                                                     \
        _Pragma("unroll")                                                      \
        for (int ii = 0; ii < 8; ++ii) {                                       \
            int row = (bb) * 16 + 2 * ii + (lane >> 5);                        \
            int j   = lane & 31;                                               \
            int d   = (j & 0x10) | ((j & 3) << 2) | ((j >> 2) & 3);            \
            unsigned v = ((unsigned)(sr[ii][0] & 255))                         \
                       | ((unsigned)(sr[ii][1] & 255) << 8)                    \
                       | ((unsigned)(sr[ii][2] & 255) << 16)                   \
                       | ((unsigned)(sr[ii][3] & 255) << 24);                  \
            lds[1024 + wave * 2048 + ((row * 32 + d) ^ ((row & 7) << 2))] = v; \
        }

    {
        i32x4 sa[8], sb[8];
        SLOAD(0, sa) SLOAD(1, sb) SWRITE(0, sa)
        SLOAD(2, sa) SWRITE(1, sb)
        SLOAD(3, sb) SWRITE(2, sa) SWRITE(3, sb)
    }

    f32x4 acc[4][2];
    #pragma unroll
    for (int st = 0; st < 4; ++st) {
        acc[st][0] = (f32x4){0.f,0.f,0.f,0.f};
        acc[st][1] = (f32x4){0.f,0.f,0.f,0.f};
    }

    const unsigned short* f0 = frag;
    const unsigned short* f1 = frag + 65536;

    // ---- compute: grp-outer (A loaded once per grp: 8 x bf16x8 = 32 VGPR) ----
    #pragma unroll
    for (int grp = 0; grp < 2; ++grp) {
        bf16x8 A0[4], A1[4];
        #pragma unroll
        for (int t = 0; t < 4; ++t) {
            int kb = by * 32 + wave * 8 + grp * 4 + t;
            A0[t] = *reinterpret_cast<const bf16x8*>(f0 + ((size_t)kb * 64 + lane) * 8);
            A1[t] = *reinterpret_cast<const bf16x8*>(f1 + ((size_t)kb * 64 + lane) * 8);
        }
        #pragma unroll
        for (int st = 0; st < 4; ++st) {
            int row = st * 16 + col;
            i32x4 cd = *reinterpret_cast<const i32x4*>(
                &lds[1024 + wave * 2048 +
                     ((row * 32 + grp * 16 + g * 4) ^ ((row & 7) << 2))]);
            f32x4 t0 = (f32x4){0.f,0.f,0.f,0.f};
            f32x4 t1 = (f32x4){0.f,0.f,0.f,0.f};
            #pragma unroll
            for (int t = 0; t < 4; ++t) {
                unsigned code = (unsigned)cd[t];
                i32x4 bu;                        // bfrag once, both halves
                bu[0] = (int)lds[wave * 256 + (code & 255u)];
                bu[1] = (int)lds[wave * 256 + ((code >> 8) & 255u)];
                bu[2] = (int)lds[wave * 256 + ((code >> 16) & 255u)];
                bu[3] = (int)lds[wave * 256 + (code >> 24)];
                bf16x8 bf = __builtin_bit_cast(bf16x8, bu);
                t0 = __builtin_amdgcn_mfma_f32_16x16x32_bf16(A0[t], bf, t0, 0, 0, 0);
                t1 = __builtin_amdgcn_mfma_f32_16x16x32_bf16(A1[t], bf, t1, 0, 0, 0);
            }
            const float sc = (grp == 0) ? scp[st].x : scp[st].y;
            #pragma unroll
            for (int j = 0; j < 4; ++j) {
                acc[st][0][j] = fmaf(sc, t0[j], acc[st][0][j]);
                acc[st][1][j] = fmaf(sc, t1[j], acc[st][1][j]);
            }
        }
    }

    // ---- epilogue: wave-private red (aliases own code region, now dead) ----
    // slot = b*64 + o  (b = h*16 + g*4 + j, o = st*16 + col)
    float* red = (float*)&lds[1024 + wave * 2048];
    #pragma unroll
    for (int st = 0; st < 4; ++st)
        #pragma unroll
        for (int j = 0; j < 4; ++j) {
            red[(0 * 16 + g * 4 + j) * 64 + st * 16 + col] = acc[st][0][j];
            red[(1 * 16 + g * 4 + j) * 64 + st * 16 + col] = acc[st][1][j];
        }
    __syncthreads();                 // the ONE barrier

    const float* rbase = (const float*)&lds[1024];
    #pragma unroll
    for (int p = 0; p < 8; ++p) {
        int b = p * 4 + wave;        // wave-uniform batch row
        float s = rbase[b * 64 + lane] + rbase[2048 + b * 64 + lane]
                + rbase[4096 + b * 64 + lane] + rbase[6144 + b * 64 + lane];
        unsafeAtomicAdd(out + (size_t)b * OUT_F + n0 + lane, s);
    }
}

// ---------------------------------------------------------------------------
extern "C" void kernel_launch(void* const* d_in, const int* in_sizes, int n_in,
                              void* d_out, int out_size, void* d_ws, size_t ws_size,
                              hipStream_t stream) {
    const float* x      = (const float*)d_in[0];
    const int*   packed = (const int*)d_in[1];
    const float* scales = (const float*)d_in[2];
    const float* bias   = (const float*)d_in[3];
    float* out = (float*)d_out;

    unsigned short* frag = (unsigned short*)d_ws;   // 256 KB

    prelude_kernel<<<408, 256, 0, stream>>>(x, bias, frag, out);
    nf4_gemm_kernel<<<dim3(GRID_N, KSPLIT), 256, 0, stream>>>(packed, scales, frag, out);
}